// Round 1
// baseline (152.851 us; speedup 1.0000x reference)
//
#include <hip/hip_runtime.h>
#include <hip/hip_bf16.h>

// Problem constants (from reference): B=64, Cin=3, H=W=64, O=16, k=7, fh=fw=58
#define O_ 16
#define CIN 3
#define KK 7
#define FH 58u
#define NK (O_ * CIN * KK * KK)          // 2352
#define PLANE 4096                        // 64*64 pixels per (b,c) plane
#define NPLANES 192                       // 64*3
#define PSPLIT 2                          // blocks per plane
#define PIX_PER_BLOCK (PLANE / PSPLIT)    // 2048
#define PIX_PER_THREAD (PIX_PER_BLOCK / 256)  // 8

// Output geometry
#define SEG 10092u                        // num_blocks = fh*fh*Cin
#define OSEG 161472u                      // O * SEG
#define OUT1 10334208u                    // B * OSEG  (one output tensor)
#define NOUT (3u * OUT1)                  // 31,002,624 floats total

// ---------------------------------------------------------------------------
// Kernel 1: per-block partial sums of relu(Kh - x) and relu(x - Km) per o.
// Each block handles 2048 pixels of ONE (b,c) plane -> c is block-uniform,
// so LDS K reads broadcast. Boundary taps masked by pushing v to +/-1e30.
// ---------------------------------------------------------------------------
__global__ __launch_bounds__(256) void sum_kernel(
    const float* __restrict__ x,
    const float* __restrict__ Kh,
    const float* __restrict__ Km,
    float* __restrict__ gsum /* 32 floats: [0..16)=hit_sum, [16..32)=miss_sum */)
{
    __shared__ float sKh[NK];
    __shared__ float sKm[NK];
    __shared__ float sred[4][32];

    for (int i = threadIdx.x; i < NK; i += 256) {
        sKh[i] = Kh[i];
        sKm[i] = Km[i];
    }
    __syncthreads();

    const int bc   = blockIdx.x / PSPLIT;     // plane index b*3+c, 0..191
    const int half = blockIdx.x % PSPLIT;
    const int c    = bc % CIN;
    const float* plane = x + bc * PLANE;

    float v[PIX_PER_THREAD];
    int   py[PIX_PER_THREAD];
    int   px[PIX_PER_THREAD];
    const int base = half * PIX_PER_BLOCK + threadIdx.x;
#pragma unroll
    for (int p = 0; p < PIX_PER_THREAD; ++p) {
        int idx = base + p * 256;
        v[p]  = plane[idx];
        py[p] = idx >> 6;
        px[p] = idx & 63;
    }

    float ah[O_], am[O_];
#pragma unroll
    for (int o = 0; o < O_; ++o) { ah[o] = 0.f; am[o] = 0.f; }

    for (int dy = 0; dy < KK; ++dy) {
        for (int dx = 0; dx < KK; ++dx) {
            float vh[PIX_PER_THREAD], vm[PIX_PER_THREAD];
#pragma unroll
            for (int p = 0; p < PIX_PER_THREAD; ++p) {
                bool ok = ((unsigned)(py[p] - dy) < FH) &&
                          ((unsigned)(px[p] - dx) < FH);
                vh[p] = ok ? v[p] :  1e30f;   // relu(kh - 1e30) == 0
                vm[p] = ok ? v[p] : -1e30f;   // relu(-1e30 - km) == 0
            }
            const int kbase = (c * KK + dy) * KK + dx;
#pragma unroll
            for (int o = 0; o < O_; ++o) {
                float kh = sKh[o * (CIN * KK * KK) + kbase];  // block-uniform -> LDS broadcast
                float km = sKm[o * (CIN * KK * KK) + kbase];
#pragma unroll
                for (int p = 0; p < PIX_PER_THREAD; ++p) {
                    ah[o] += fmaxf(kh - vh[p], 0.f);
                    am[o] += fmaxf(vm[p] - km, 0.f);
                }
            }
        }
    }

    // wave-level shuffle reduction, then cross-wave via LDS, then 32 atomics
    const int lane = threadIdx.x & 63;
    const int wid  = threadIdx.x >> 6;
#pragma unroll
    for (int o = 0; o < O_; ++o) {
        float h = ah[o], m = am[o];
#pragma unroll
        for (int off = 32; off > 0; off >>= 1) {
            h += __shfl_down(h, off);
            m += __shfl_down(m, off);
        }
        if (lane == 0) { sred[wid][o] = h; sred[wid][O_ + o] = m; }
    }
    __syncthreads();
    if (threadIdx.x < 32) {
        float s = sred[0][threadIdx.x] + sred[1][threadIdx.x] +
                  sred[2][threadIdx.x] + sred[3][threadIdx.x];
        atomicAdd(&gsum[threadIdx.x], s);
    }
}

// ---------------------------------------------------------------------------
// Kernel 2: fold the 32 sums into the 48 broadcast values.
//   s_hit = -hit_sum ; s_miss = +miss_sum
//   vals[0..16)  = F_map  = s_hit - s_miss
//   vals[16..32) = s_hit
//   vals[32..48) = s_miss
// ---------------------------------------------------------------------------
__global__ void finalize_kernel(const float* __restrict__ gsum,
                                float* __restrict__ vals)
{
    int o = threadIdx.x;
    if (o < O_) {
        float h = -gsum[o];
        float m =  gsum[O_ + o];
        vals[o]          = h - m;
        vals[O_ + o]     = h;
        vals[2 * O_ + o] = m;
    }
}

// ---------------------------------------------------------------------------
// Kernel 3: broadcast-fill the three output tensors (float4 stores).
// Flat layout per output: n = b*OSEG + o*SEG + r ; value depends only on o.
// SEG % 4 == 0 and OUT1 % 4 == 0, so every aligned float4 has a single value.
// ---------------------------------------------------------------------------
__global__ __launch_bounds__(256) void fill_kernel(
    const float* __restrict__ vals,
    float4* __restrict__ out, unsigned n4)
{
    __shared__ float sv[48];
    if (threadIdx.x < 48) sv[threadIdx.x] = vals[threadIdx.x];
    __syncthreads();

    unsigned stride = gridDim.x * blockDim.x;
    for (unsigned i = blockIdx.x * blockDim.x + threadIdx.x; i < n4; i += stride) {
        unsigned byte_base = i * 4u;                  // float index
        unsigned w   = byte_base / OUT1;              // which output (0..2)
        unsigned rem = byte_base - w * OUT1;
        unsigned o   = (rem % OSEG) / SEG;            // output channel 0..15
        float val = sv[w * O_ + o];
        out[i] = make_float4(val, val, val, val);
    }
}

extern "C" void kernel_launch(void* const* d_in, const int* in_sizes, int n_in,
                              void* d_out, int out_size, void* d_ws, size_t ws_size,
                              hipStream_t stream)
{
    const float* x  = (const float*)d_in[0];
    const float* Kh = (const float*)d_in[1];
    const float* Km = (const float*)d_in[2];
    float* out  = (float*)d_out;
    float* gsum = (float*)d_ws;        // 32 floats
    float* vals = gsum + 32;           // 48 floats

    hipMemsetAsync(gsum, 0, 32 * sizeof(float), stream);

    sum_kernel<<<NPLANES * PSPLIT, 256, 0, stream>>>(x, Kh, Km, gsum);
    finalize_kernel<<<1, 64, 0, stream>>>(gsum, vals);

    unsigned n4 = NOUT / 4u;           // 7,750,656 float4 stores
    fill_kernel<<<4096, 256, 0, stream>>>(vals, (float4*)out, n4);
}

// Round 2
// 119.827 us; speedup vs baseline: 1.2756x; 1.2756x over previous
//
#include <hip/hip_runtime.h>
#include <hip/hip_bf16.h>

// Problem constants: B=64, Cin=3, H=W=64, O=16, k=7, fh=fw=58
#define O_ 16
#define CIN 3
#define KK 7
#define NTAP 49
#define FH 58u
#define NK (O_ * CIN * KK * KK)          // 2352
#define PLANE 4096                        // 64*64 pixels per (b,c) plane
#define NPLANES 192                       // 64*3
#define PSPLIT 4                          // blocks per plane
#define PIX_PER_BLOCK (PLANE / PSPLIT)    // 1024
#define PIX_PER_THREAD (PIX_PER_BLOCK / 256)  // 4

// valid pixels per tap = 58*58 = 3364; invalid = 4096-3364 = 732
#define VALID_PER_TAP_B 215296.0f         // 3364 * B(=64)
#define INVALID_PER_TAP_B 46848.0f        // 732 * B

// Output geometry
#define SEG 10092u                        // fh*fh*Cin
#define OSEG 161472u                      // O * SEG
#define OUT1 10334208u                    // B * OSEG
#define NOUT (3u * OUT1)                  // 31,002,624 floats

// ---------------------------------------------------------------------------
// Kernel 1: accumulate  Sabs_h[o] = sum |kh - vv|,  Sabs_m[o] = sum |km - vv|
// over ALL (pixel, tap) pairs with vv = valid ? v : 0, plus Wtot = sum v*w.
// relu sums are reconstructed in finalize via relu(t) = (t + |t|)/2.
// Each block: 1024 pixels of ONE (b,c) plane -> c block-uniform, K reads are
// LDS broadcasts (ds_read_b128 of interleaved (kh,km) pairs).
// ---------------------------------------------------------------------------
__global__ __launch_bounds__(256) void sum_kernel(
    const float* __restrict__ x,
    const float* __restrict__ Kh,
    const float* __restrict__ Km,
    float* __restrict__ gsum /* 33 floats: [0..16) Sabs_h, [16..32) Sabs_m, [32] Wtot */)
{
    __shared__ float4 sK4[CIN * NTAP * 8];   // per tap: 8 float4 = (kh[o],km[o]) o=0..15
    __shared__ float sred[4][33];
    float* sKf = (float*)sK4;

    for (int i = threadIdx.x; i < NK; i += 256) {
        int o = i / 147;            // 147 = CIN*49
        int r = i - o * 147;
        int c = r / NTAP;
        int t = r - c * NTAP;
        int base = (c * NTAP + t) * 32 + 2 * o;
        sKf[base]     = Kh[i];
        sKf[base + 1] = Km[i];
    }
    __syncthreads();

    const int bc   = blockIdx.x / PSPLIT;     // plane index b*3+c
    const int part = blockIdx.x % PSPLIT;
    const int c    = bc % CIN;
    const float* plane = x + bc * PLANE;

    const int base = part * PIX_PER_BLOCK + threadIdx.x;
    const int px0  = base & 63;               // constant across p (stride 256 = 4 rows)
    const int py0  = base >> 6;

    float v[PIX_PER_THREAD];
#pragma unroll
    for (int p = 0; p < PIX_PER_THREAD; ++p)
        v[p] = plane[base + p * 256];

    // Wtot partial: w(py,px) = wy*wx, wy = min(min(py+1,7), 64-py)
    float wsum = 0.f;
    {
        int wx = min(min(px0 + 1, 7), 64 - px0);
#pragma unroll
        for (int p = 0; p < PIX_PER_THREAD; ++p) {
            int py = py0 + 4 * p;
            int wy = min(min(py + 1, 7), 64 - py);
            wsum += v[p] * (float)(wy * wx);
        }
    }

    float ah[O_], am[O_];
#pragma unroll
    for (int o = 0; o < O_; ++o) { ah[o] = 0.f; am[o] = 0.f; }

#pragma unroll 1
    for (int dy = 0; dy < KK; ++dy) {
        bool oky[PIX_PER_THREAD];
#pragma unroll
        for (int p = 0; p < PIX_PER_THREAD; ++p)
            oky[p] = ((unsigned)(py0 + 4 * p - dy) < FH);
#pragma unroll 1
        for (int dx = 0; dx < KK; ++dx) {
            const bool okx = ((unsigned)(px0 - dx) < FH);
            float vv[PIX_PER_THREAD];
#pragma unroll
            for (int p = 0; p < PIX_PER_THREAD; ++p)
                vv[p] = (okx && oky[p]) ? v[p] : 0.f;

            const float4* q = &sK4[(c * NTAP + dy * KK + dx) * 8];
#pragma unroll
            for (int j = 0; j < 8; ++j) {
                float4 kq = q[j];                  // broadcast ds_read_b128
                const int o0 = 2 * j, o1 = 2 * j + 1;
#pragma unroll
                for (int p = 0; p < PIX_PER_THREAD; ++p) {
                    ah[o0] += fabsf(kq.x - vv[p]); // v_sub + v_add(|src|)
                    am[o0] += fabsf(kq.y - vv[p]);
                    ah[o1] += fabsf(kq.z - vv[p]);
                    am[o1] += fabsf(kq.w - vv[p]);
                }
            }
        }
    }

    // wave shuffle reduce -> LDS -> 33 atomics per block
    const int lane = threadIdx.x & 63;
    const int wid  = threadIdx.x >> 6;
#pragma unroll
    for (int o = 0; o < O_; ++o) {
        float h = ah[o], m = am[o];
#pragma unroll
        for (int off = 32; off > 0; off >>= 1) {
            h += __shfl_down(h, off);
            m += __shfl_down(m, off);
        }
        if (lane == 0) { sred[wid][o] = h; sred[wid][O_ + o] = m; }
    }
    {
        float s = wsum;
#pragma unroll
        for (int off = 32; off > 0; off >>= 1) s += __shfl_down(s, off);
        if (lane == 0) sred[wid][32] = s;
    }
    __syncthreads();
    if (threadIdx.x < 33) {
        float s = sred[0][threadIdx.x] + sred[1][threadIdx.x] +
                  sred[2][threadIdx.x] + sred[3][threadIdx.x];
        atomicAdd(&gsum[threadIdx.x], s);
    }
}

// ---------------------------------------------------------------------------
// Kernel 2: reconstruct s_hit/s_miss from abs sums + analytic linear terms.
//  s_hit  = -0.5*((3364*B*KsumH - Wtot) + (SabsH_raw - 732*B*KabsH))
//  s_miss =  0.5*((Wtot - 3364*B*KsumM) + (SabsM_raw - 732*B*KabsM))
// ---------------------------------------------------------------------------
__global__ __launch_bounds__(256) void finalize_kernel(
    const float* __restrict__ gsum,
    const float* __restrict__ Kh,
    const float* __restrict__ Km,
    float* __restrict__ vals)
{
    __shared__ float red[16][16][4];
    const int o = threadIdx.x & 15;
    const int j = threadIdx.x >> 4;
    float sh = 0.f, bh = 0.f, sm = 0.f, bm = 0.f;
    for (int t = j; t < 147; t += 16) {
        float a = Kh[o * 147 + t];
        float b = Km[o * 147 + t];
        sh += a; bh += fabsf(a);
        sm += b; bm += fabsf(b);
    }
    red[j][o][0] = sh; red[j][o][1] = bh;
    red[j][o][2] = sm; red[j][o][3] = bm;
    __syncthreads();
    if (threadIdx.x < 16) {
        const int oo = threadIdx.x;
        float KsumH = 0.f, KabsH = 0.f, KsumM = 0.f, KabsM = 0.f;
        for (int jj = 0; jj < 16; ++jj) {
            KsumH += red[jj][oo][0]; KabsH += red[jj][oo][1];
            KsumM += red[jj][oo][2]; KabsM += red[jj][oo][3];
        }
        const float Wtot  = gsum[32];
        const float SabsH = gsum[oo]      - INVALID_PER_TAP_B * KabsH;
        const float SabsM = gsum[16 + oo] - INVALID_PER_TAP_B * KabsM;
        const float s_hit  = -0.5f * ((VALID_PER_TAP_B * KsumH - Wtot) + SabsH);
        const float s_miss =  0.5f * ((Wtot - VALID_PER_TAP_B * KsumM) + SabsM);
        vals[oo]          = s_hit - s_miss;
        vals[O_ + oo]     = s_hit;
        vals[2 * O_ + oo] = s_miss;
    }
}

// ---------------------------------------------------------------------------
// Kernel 3: broadcast-fill the three outputs (float4 stores, write-bound).
// ---------------------------------------------------------------------------
__global__ __launch_bounds__(256) void fill_kernel(
    const float* __restrict__ vals,
    float4* __restrict__ out, unsigned n4)
{
    __shared__ float sv[48];
    if (threadIdx.x < 48) sv[threadIdx.x] = vals[threadIdx.x];
    __syncthreads();

    unsigned stride = gridDim.x * blockDim.x;
    for (unsigned i = blockIdx.x * blockDim.x + threadIdx.x; i < n4; i += stride) {
        unsigned fbase = i * 4u;
        unsigned w   = fbase / OUT1;
        unsigned rem = fbase - w * OUT1;
        unsigned o   = (rem % OSEG) / SEG;
        float val = sv[w * O_ + o];
        out[i] = make_float4(val, val, val, val);
    }
}

extern "C" void kernel_launch(void* const* d_in, const int* in_sizes, int n_in,
                              void* d_out, int out_size, void* d_ws, size_t ws_size,
                              hipStream_t stream)
{
    const float* x  = (const float*)d_in[0];
    const float* Kh = (const float*)d_in[1];
    const float* Km = (const float*)d_in[2];
    float* out  = (float*)d_out;
    float* gsum = (float*)d_ws;        // 33 floats
    float* vals = gsum + 64;           // 48 floats

    hipMemsetAsync(gsum, 0, 34 * sizeof(float), stream);

    sum_kernel<<<NPLANES * PSPLIT, 256, 0, stream>>>(x, Kh, Km, gsum);
    finalize_kernel<<<1, 256, 0, stream>>>(gsum, Kh, Km, vals);

    unsigned n4 = NOUT / 4u;
    fill_kernel<<<4096, 256, 0, stream>>>(vals, (float4*)out, n4);
}